// Round 7
// baseline (56.409 us; speedup 1.0000x reference)
//
#include <hip/hip_runtime.h>
#include <math.h>

#define FF 20
#define TPB 256              // 4 waves per block
#define TILES_PER_WAVE 16    // 16 rows per tile -> 256 rows per wave
#define BT 4                 // tiles per load batch

typedef __fp16 half2v __attribute__((ext_vector_type(2)));
typedef __fp16 half8 __attribute__((ext_vector_type(8)));
typedef float f32x4 __attribute__((ext_vector_type(4)));

// ---------------------------------------------------------------------------
// Setup (1 block, 256 threads): zero the finish counter and build the four
// f16 MFMA A-fragments (per-lane layout for 16x16x32):
//   f=0,1: GEMM1 A = At_ext, row m=(f&1)*16+(l&15), k=i
//          At[m][i] = sum_j W[j,i]R[j,m] (i<20); i==20 -> 1 + sum_j b_j R[j,m]
//   f=2,3: GEMM2 A = W_ext, row n=(f&1)*16+(l&15), k=m; m==20 -> b[n]
//   k(e) = e<4 ? 4g+e : 16+4g+(e-4), g=(l>>4)
// ---------------------------------------------------------------------------
__global__ void mlp_setup(const float* __restrict__ W, const float* __restrict__ b,
                          const float* __restrict__ R, __fp16* __restrict__ frag,
                          unsigned int* __restrict__ counter) {
    int t = threadIdx.x;                 // t = f*64 + l
    if (t == 0) *counter = 0u;
    int f = t >> 6, l = t & 63;
    int g = l >> 4, p = l & 15;
    int row = (f & 1) * 16 + p;
    #pragma unroll
    for (int e = 0; e < 8; ++e) {
        int k = (e < 4) ? (4 * g + e) : (16 + 4 * g + (e - 4));
        float v = 0.f;
        if (f < 2) {                     // GEMM1 weights
            if (row < FF) {
                if (k < FF) {
                    float s = 0.f;
                    for (int j = 0; j < FF; ++j) s = fmaf(W[j * FF + k], R[j * FF + row], s);
                    v = s;
                } else if (k == FF) {
                    float s = 1.0f;
                    for (int j = 0; j < FF; ++j) s = fmaf(b[j], R[j * FF + row], s);
                    v = s;
                }
            }
        } else {                         // GEMM2 weights
            if (row < FF) {
                if (k < FF) v = W[row * FF + k];
                else if (k == FF) v = b[row];
            }
        }
        frag[t * 8 + e] = (__fp16)v;
    }
}

// ---------------------------------------------------------------------------
// Main: per wave TILES_PER_WAVE 16-row tiles. B1 = xT (f16) -> 2 MFMA (h2T)
// -> relu/pack (C/D row pattern == A/B k pattern, zero cross-lane) -> 2 MFMA
// (h3T) -> per-lane sum/|sum| -> wave/block reduce -> partials[block];
// last finishing block reduces partials with ONE WAVE (shfl, no big LDS),
// computes halving count, writes the scalar.
// __launch_bounds__(256, 4): pin 4 waves/EU target -> VGPR cap 128, so the
// allocator keeps the BT=4 load batch (8 float4) in flight (R6's 44-VGPR
// codegen serialized the loads and tripled runtime).
// ---------------------------------------------------------------------------
__global__ __launch_bounds__(TPB, 4) void mlp_main(
    const float* __restrict__ x, const __fp16* __restrict__ frag,
    unsigned int* __restrict__ counter, double2* __restrict__ partials,
    float* __restrict__ out, int nrows, int ntiles, int nblocks)
{
    const int t = threadIdx.x;
    const int l = t & 63;
    const int g = l >> 4;        // 0..3
    const int r = l & 15;        // row within tile == output col

    // persistent A-fragments (16 VGPRs)
    const half8 A10 = *reinterpret_cast<const half8*>(frag + (0 * 64 + l) * 8);
    const half8 A11 = *reinterpret_cast<const half8*>(frag + (1 * 64 + l) * 8);
    const half8 A20 = *reinterpret_cast<const half8*>(frag + (2 * 64 + l) * 8);
    const half8 A21 = *reinterpret_cast<const half8*>(frag + (3 * 64 + l) * 8);

    const int wave_id = blockIdx.x * (TPB / 64) + (t >> 6);
    const long tile0 = (long)wave_id * TILES_PER_WAVE;

    float psum = 0.f, pabs = 0.f;
    const f32x4 zero = {0.f, 0.f, 0.f, 0.f};

    for (int bt = 0; bt < TILES_PER_WAVE / BT; ++bt) {
        float4 xa[BT], xb[BT];
        #pragma unroll
        for (int u = 0; u < BT; ++u) {
            long tile = tile0 + bt * BT + u;
            xa[u] = make_float4(0.f, 0.f, 0.f, 0.f);
            xb[u] = make_float4(0.f, 0.f, 0.f, 0.f);
            if (tile < ntiles) {
                long row = tile * 16 + r;
                if (row < nrows) {
                    const float* rowp = x + row * FF;
                    xa[u] = *reinterpret_cast<const float4*>(rowp + 4 * g);
                    if (g == 0)
                        xb[u] = *reinterpret_cast<const float4*>(rowp + 16);
                }
            }
        }
        #pragma unroll
        for (int u = 0; u < BT; ++u) {
            long tile = tile0 + bt * BT + u;
            // ---- B1 fragment: x row r, k=i per doubled-K layout ----
            half8 B1;
            half2v p0 = __builtin_amdgcn_cvt_pkrtz(xa[u].x, xa[u].y);
            half2v p1 = __builtin_amdgcn_cvt_pkrtz(xa[u].z, xa[u].w);
            B1[0] = p0[0]; B1[1] = p0[1]; B1[2] = p1[0]; B1[3] = p1[1];
            if (g == 0) {
                half2v p2 = __builtin_amdgcn_cvt_pkrtz(xb[u].x, xb[u].y);
                half2v p3 = __builtin_amdgcn_cvt_pkrtz(xb[u].z, xb[u].w);
                B1[4] = p2[0]; B1[5] = p2[1]; B1[6] = p3[0]; B1[7] = p3[1];
            } else if (g == 1) {
                B1[4] = (__fp16)1.0f;     // i == 20 -> bias column
                B1[5] = (__fp16)0.f; B1[6] = (__fp16)0.f; B1[7] = (__fp16)0.f;
            } else {
                B1[4] = (__fp16)0.f; B1[5] = (__fp16)0.f;
                B1[6] = (__fp16)0.f; B1[7] = (__fp16)0.f;
            }
            // ---- GEMM1: h2T[m][r] ----
            f32x4 c0 = __builtin_amdgcn_mfma_f32_16x16x32_f16(A10, B1, zero, 0, 0, 0);
            f32x4 c1 = __builtin_amdgcn_mfma_f32_16x16x32_f16(A11, B1, zero, 0, 0, 0);
            // ---- relu + pack ----
            half8 B2;
            half2v q0 = __builtin_amdgcn_cvt_pkrtz(fmaxf(c0[0], 0.f), fmaxf(c0[1], 0.f));
            half2v q1 = __builtin_amdgcn_cvt_pkrtz(fmaxf(c0[2], 0.f), fmaxf(c0[3], 0.f));
            half2v q2 = __builtin_amdgcn_cvt_pkrtz(fmaxf(c1[0], 0.f), fmaxf(c1[1], 0.f));
            half2v q3 = __builtin_amdgcn_cvt_pkrtz(fmaxf(c1[2], 0.f), fmaxf(c1[3], 0.f));
            B2[0] = q0[0]; B2[1] = q0[1]; B2[2] = q1[0]; B2[3] = q1[1];
            B2[4] = q2[0]; B2[5] = q2[1]; B2[6] = q3[0]; B2[7] = q3[1];
            if (g == 1) B2[4] = (__fp16)1.0f;   // m == 20 -> bias column
            // ---- GEMM2: h3T[n][r] ----
            f32x4 d0 = __builtin_amdgcn_mfma_f32_16x16x32_f16(A20, B2, zero, 0, 0, 0);
            f32x4 d1 = __builtin_amdgcn_mfma_f32_16x16x32_f16(A21, B2, zero, 0, 0, 0);
            if (tile * 16 + r < nrows) {
                #pragma unroll
                for (int q = 0; q < 4; ++q) {
                    psum += d0[q];            pabs += fabsf(d0[q]);
                    psum += d1[q];            pabs += fabsf(d1[q]);
                }
            }
        }
    }

    // ---- wave + block reduction ----
    #pragma unroll
    for (int off = 32; off > 0; off >>= 1) {
        psum += __shfl_down(psum, off, 64);
        pabs += __shfl_down(pabs, off, 64);
    }
    __shared__ double wsum[TPB / 64], wabs[TPB / 64];
    __shared__ int isLast;
    if ((t & 63) == 0) { wsum[t >> 6] = (double)psum; wabs[t >> 6] = (double)pabs; }
    __syncthreads();
    if (t == 0) {
        double bs = 0.0, ba = 0.0;
        #pragma unroll
        for (int w = 0; w < TPB / 64; ++w) { bs += wsum[w]; ba += wabs[w]; }
        partials[blockIdx.x] = make_double2(bs, ba);
        __threadfence();                          // release partials
        unsigned int old = atomicAdd(counter, 1u);
        isLast = (old == (unsigned int)(nblocks - 1)) ? 1 : 0;
    }
    __syncthreads();
    // ---- last block: ONE WAVE reduces all partials via shfl (no big LDS) ----
    if (isLast && t < 64) {
        double sg = 0.0, a = 0.0;
        for (int i = t; i < nblocks; i += 64) {
            double px = __hip_atomic_load(&partials[i].x, __ATOMIC_RELAXED,
                                          __HIP_MEMORY_SCOPE_AGENT);
            double py = __hip_atomic_load(&partials[i].y, __ATOMIC_RELAXED,
                                          __HIP_MEMORY_SCOPE_AGENT);
            sg += px; a += py;
        }
        #pragma unroll
        for (int off = 32; off > 0; off >>= 1) {
            sg += __shfl_down(sg, off, 64);
            a  += __shfl_down(a,  off, 64);
        }
        if (t == 0) {
            double s = a;
            int k = 0;
            while (s > 1.0 && k < 4000) { s *= 0.5; ++k; }
            out[0] = (float)ldexp(sg, -k);
        }
    }
}

extern "C" void kernel_launch(void* const* d_in, const int* in_sizes, int n_in,
                              void* d_out, int out_size, void* d_ws, size_t ws_size,
                              hipStream_t stream) {
    const float* x = (const float*)d_in[0];
    const float* W = (const float*)d_in[1];
    const float* b = (const float*)d_in[2];
    const float* R = (const float*)d_in[3];
    float* out = (float*)d_out;

    // d_ws: [0,4KB) A-fragments (4*64*8 f16), [4KB,4.25KB) counter,
    //       [8KB, ...) double2 partials
    __fp16* frag = (__fp16*)d_ws;
    unsigned int* counter = (unsigned int*)((char*)d_ws + 4096);
    double2* partials = (double2*)((char*)d_ws + 8192);

    int nrows = in_sizes[0] / FF;
    int ntiles = (nrows + 15) / 16;
    int waves = (ntiles + TILES_PER_WAVE - 1) / TILES_PER_WAVE;
    int blocks = (waves + (TPB / 64) - 1) / (TPB / 64);

    hipLaunchKernelGGL(mlp_setup, dim3(1), dim3(256), 0, stream, W, b, R, frag, counter);
    hipLaunchKernelGGL(mlp_main, dim3(blocks), dim3(TPB), 0, stream,
                       x, frag, counter, partials, out, nrows, ntiles, blocks);
}

// Round 8
// 30.756 us; speedup vs baseline: 1.8341x; 1.8341x over previous
//
#include <hip/hip_runtime.h>
#include <math.h>

#define FF 20
#define TPB 256              // 4 waves per block
#define TPW 8                // tiles per wave, ALL loaded up-front (one batch)

typedef __fp16 half2v __attribute__((ext_vector_type(2)));
typedef __fp16 half8 __attribute__((ext_vector_type(8)));
typedef float f32x4 __attribute__((ext_vector_type(4)));

// ---------------------------------------------------------------------------
// Setup (1 block): build the four f16 MFMA A-fragments (16x16x32 layout):
//   f=0,1: GEMM1 A = At_ext, row m=(f&1)*16+(l&15), k=i
//          At[m][i] = sum_j W[j,i]R[j,m] (i<20); i==20 -> 1 + sum_j b_j R[j,m]
//   f=2,3: GEMM2 A = W_ext, row n=(f&1)*16+(l&15), k=m; m==20 -> b[n]
//   k(e) = e<4 ? 4g+e : 16+4g+(e-4), g=(l>>4)
// ---------------------------------------------------------------------------
__global__ void mlp_setup(const float* __restrict__ W, const float* __restrict__ b,
                          const float* __restrict__ R, __fp16* __restrict__ frag) {
    int t = threadIdx.x;                 // t = f*64 + l
    int f = t >> 6, l = t & 63;
    int g = l >> 4, p = l & 15;
    int row = (f & 1) * 16 + p;
    #pragma unroll
    for (int e = 0; e < 8; ++e) {
        int k = (e < 4) ? (4 * g + e) : (16 + 4 * g + (e - 4));
        float v = 0.f;
        if (f < 2) {                     // GEMM1 weights
            if (row < FF) {
                if (k < FF) {
                    float s = 0.f;
                    for (int j = 0; j < FF; ++j) s = fmaf(W[j * FF + k], R[j * FF + row], s);
                    v = s;
                } else if (k == FF) {
                    float s = 1.0f;
                    for (int j = 0; j < FF; ++j) s = fmaf(b[j], R[j * FF + row], s);
                    v = s;
                }
            }
        } else {                         // GEMM2 weights
            if (row < FF) {
                if (k < FF) v = W[row * FF + k];
                else if (k == FF) v = b[row];
            }
        }
        frag[t * 8 + e] = (__fp16)v;
    }
}

// ---------------------------------------------------------------------------
// Main: per wave, ONE batch of TPW=8 contiguous 16-row tiles. All 8 xa + 8 xb
// loads are issued back-to-back at wave start (max VMEM in flight: 160B/lane),
// then 8x{B1 pack -> 2 MFMA -> relu/pack -> 2 MFMA -> sum/|sum|}. Simple
// 3-kernel structure: block partial out, no fused epilogue (R6/R7 showed the
// fused tail triggers a 40-VGPR load-serializing codegen, 3x slower).
// ---------------------------------------------------------------------------
__global__ __launch_bounds__(TPB) void mlp_main(
    const float* __restrict__ x, const __fp16* __restrict__ frag,
    double2* __restrict__ partials, int nrows, int ntiles)
{
    const int t = threadIdx.x;
    const int l = t & 63;
    const int g = l >> 4;        // 0..3  (k-chunk)
    const int r = l & 15;        // row within tile == output col

    // persistent A-fragments (16 VGPRs)
    const half8 A10 = *reinterpret_cast<const half8*>(frag + (0 * 64 + l) * 8);
    const half8 A11 = *reinterpret_cast<const half8*>(frag + (1 * 64 + l) * 8);
    const half8 A20 = *reinterpret_cast<const half8*>(frag + (2 * 64 + l) * 8);
    const half8 A21 = *reinterpret_cast<const half8*>(frag + (3 * 64 + l) * 8);

    const int wave_id = blockIdx.x * (TPB / 64) + (t >> 6);
    const int base_row = wave_id * (TPW * 16) + r;

    // ---- issue ALL loads up front (10 vector-load instructions in flight) ----
    float4 xa[TPW], xb[TPW];
    const float* rowp = x + (size_t)base_row * FF;
    #pragma unroll
    for (int u = 0; u < TPW; ++u) {
        int row = base_row + u * 16;
        xa[u] = make_float4(0.f, 0.f, 0.f, 0.f);
        if (row < nrows)
            xa[u] = *reinterpret_cast<const float4*>(rowp + (size_t)u * 16 * FF + 4 * g);
    }
    #pragma unroll
    for (int u = 0; u < TPW; ++u) {
        int row = base_row + u * 16;
        xb[u] = make_float4(0.f, 0.f, 0.f, 0.f);
        if (g == 0 && row < nrows)
            xb[u] = *reinterpret_cast<const float4*>(rowp + (size_t)u * 16 * FF + 16);
    }

    float psum = 0.f, pabs = 0.f;
    const f32x4 zero = {0.f, 0.f, 0.f, 0.f};

    #pragma unroll
    for (int u = 0; u < TPW; ++u) {
        // ---- B1 fragment: x row r, k=i per doubled-K layout ----
        half8 B1;
        half2v p0 = __builtin_amdgcn_cvt_pkrtz(xa[u].x, xa[u].y);
        half2v p1 = __builtin_amdgcn_cvt_pkrtz(xa[u].z, xa[u].w);
        B1[0] = p0[0]; B1[1] = p0[1]; B1[2] = p1[0]; B1[3] = p1[1];
        if (g == 0) {
            half2v p2 = __builtin_amdgcn_cvt_pkrtz(xb[u].x, xb[u].y);
            half2v p3 = __builtin_amdgcn_cvt_pkrtz(xb[u].z, xb[u].w);
            B1[4] = p2[0]; B1[5] = p2[1]; B1[6] = p3[0]; B1[7] = p3[1];
        } else if (g == 1) {
            B1[4] = (__fp16)1.0f;     // i == 20 -> bias column
            B1[5] = (__fp16)0.f; B1[6] = (__fp16)0.f; B1[7] = (__fp16)0.f;
        } else {
            B1[4] = (__fp16)0.f; B1[5] = (__fp16)0.f;
            B1[6] = (__fp16)0.f; B1[7] = (__fp16)0.f;
        }
        // ---- GEMM1: h2T[m][r] ----
        f32x4 c0 = __builtin_amdgcn_mfma_f32_16x16x32_f16(A10, B1, zero, 0, 0, 0);
        f32x4 c1 = __builtin_amdgcn_mfma_f32_16x16x32_f16(A11, B1, zero, 0, 0, 0);
        // ---- relu + pack (C/D row pattern == A/B k pattern, no cross-lane) ----
        half8 B2;
        half2v q0 = __builtin_amdgcn_cvt_pkrtz(fmaxf(c0[0], 0.f), fmaxf(c0[1], 0.f));
        half2v q1 = __builtin_amdgcn_cvt_pkrtz(fmaxf(c0[2], 0.f), fmaxf(c0[3], 0.f));
        half2v q2 = __builtin_amdgcn_cvt_pkrtz(fmaxf(c1[0], 0.f), fmaxf(c1[1], 0.f));
        half2v q3 = __builtin_amdgcn_cvt_pkrtz(fmaxf(c1[2], 0.f), fmaxf(c1[3], 0.f));
        B2[0] = q0[0]; B2[1] = q0[1]; B2[2] = q1[0]; B2[3] = q1[1];
        B2[4] = q2[0]; B2[5] = q2[1]; B2[6] = q3[0]; B2[7] = q3[1];
        if (g == 1) B2[4] = (__fp16)1.0f;   // m == 20 -> bias column
        // ---- GEMM2: h3T[n][r] ----
        f32x4 d0 = __builtin_amdgcn_mfma_f32_16x16x32_f16(A20, B2, zero, 0, 0, 0);
        f32x4 d1 = __builtin_amdgcn_mfma_f32_16x16x32_f16(A21, B2, zero, 0, 0, 0);
        if (base_row + u * 16 < nrows) {
            #pragma unroll
            for (int q = 0; q < 4; ++q) {
                psum += d0[q];            pabs += fabsf(d0[q]);
                psum += d1[q];            pabs += fabsf(d1[q]);
            }
        }
    }

    // ---- wave + block reduction -> one double2 per block ----
    #pragma unroll
    for (int off = 32; off > 0; off >>= 1) {
        psum += __shfl_down(psum, off, 64);
        pabs += __shfl_down(pabs, off, 64);
    }
    __shared__ double wsum[TPB / 64], wabs[TPB / 64];
    if ((t & 63) == 0) { wsum[t >> 6] = (double)psum; wabs[t >> 6] = (double)pabs; }
    __syncthreads();
    if (t == 0) {
        double bs = 0.0, ba = 0.0;
        #pragma unroll
        for (int w = 0; w < TPB / 64; ++w) { bs += wsum[w]; ba += wabs[w]; }
        partials[blockIdx.x] = make_double2(bs, ba);
    }
}

// ---------------------------------------------------------------------------
// Final: deterministic tree-reduce of block partials; halving count; output.
// ---------------------------------------------------------------------------
__global__ __launch_bounds__(256) void mlp_final(const double2* __restrict__ parts,
                                                 int nparts, float* __restrict__ out) {
    __shared__ double s_sum[256], s_abs[256];
    int t = threadIdx.x;
    double a = 0.0, sg = 0.0;
    for (int i = t; i < nparts; i += 256) { sg += parts[i].x; a += parts[i].y; }
    s_sum[t] = sg; s_abs[t] = a;
    __syncthreads();
    for (int off = 128; off > 0; off >>= 1) {
        if (t < off) { s_sum[t] += s_sum[t + off]; s_abs[t] += s_abs[t + off]; }
        __syncthreads();
    }
    if (t == 0) {
        double s = s_abs[0];
        int k = 0;
        while (s > 1.0 && k < 4000) { s *= 0.5; ++k; }
        out[0] = (float)ldexp(s_sum[0], -k);
    }
}

extern "C" void kernel_launch(void* const* d_in, const int* in_sizes, int n_in,
                              void* d_out, int out_size, void* d_ws, size_t ws_size,
                              hipStream_t stream) {
    const float* x = (const float*)d_in[0];
    const float* W = (const float*)d_in[1];
    const float* b = (const float*)d_in[2];
    const float* R = (const float*)d_in[3];
    float* out = (float*)d_out;

    // d_ws: [0,4KB) A-fragments (4*64*8 f16), [8KB, ...) double2 partials
    __fp16* frag = (__fp16*)d_ws;
    double2* partials = (double2*)((char*)d_ws + 8192);

    int nrows = in_sizes[0] / FF;
    int ntiles = (nrows + 15) / 16;
    int waves = (ntiles + TPW - 1) / TPW;
    int blocks = (waves + (TPB / 64) - 1) / (TPB / 64);

    hipLaunchKernelGGL(mlp_setup, dim3(1), dim3(256), 0, stream, W, b, R, frag);
    hipLaunchKernelGGL(mlp_main, dim3(blocks), dim3(TPB), 0, stream,
                       x, frag, partials, nrows, ntiles);
    hipLaunchKernelGGL(mlp_final, dim3(1), dim3(256), 0, stream, partials, blocks, out);
}